// Round 1
// baseline (71.303 us; speedup 1.0000x reference)
//
#include <hip/hip_runtime.h>
#include <hip/hip_bf16.h>

#define ALPHA 0.2f
#define NEG_BIG -9000000000000000.0f

typedef __attribute__((ext_vector_type(8))) short bf16x8;
typedef __attribute__((ext_vector_type(8))) unsigned short u16x8;
typedef __attribute__((ext_vector_type(4))) float f32x4;
typedef __attribute__((ext_vector_type(4))) int i32x4;

__device__ __forceinline__ unsigned short f2bf(float x) {
    // round-to-nearest-even fp32 -> bf16 (finite inputs only)
    unsigned int u = __float_as_uint(x);
    unsigned int r = (u + 0x7FFFu + ((u >> 16) & 1u)) >> 16;
    return (unsigned short)r;
}

// ---------------------------------------------------------------------------
// Kernel A: Wh = h @ W (fp32), si = Wh@a1, sj = Wh@a2, WhT = bf16(Wh)^T
// h: [B*N][128] fp32, W: [128][64] fp32, a: [128] fp32
// WhT: [B][64][2048] bf16, si/sj: [B*N] fp32
// Block: 256 threads, 64 rows. Grid: 16384/64 = 256.
// ---------------------------------------------------------------------------
__global__ __launch_bounds__(256) void gat_precompute(
    const float* __restrict__ h, const float* __restrict__ W,
    const float* __restrict__ a, unsigned short* __restrict__ WhT,
    float* __restrict__ si, float* __restrict__ sj)
{
    __shared__ float h_lds[64][128];
    __shared__ float wh_lds[64][65];   // +1 pad: conflict-free transpose reads
    const int tid  = threadIdx.x;
    const int lane = tid & 63;
    const int wave = tid >> 6;
    const long long row0 = (long long)blockIdx.x * 64;

    // stage 64x128 h tile, fully coalesced float4
    {
        const float4* s4 = (const float4*)(h + row0 * 128);
        #pragma unroll
        for (int i = 0; i < 8; ++i) {
            int idx = tid + i * 256;          // 0..2047 float4s
            float4 v = s4[idx];
            int r = idx >> 5;
            int f = (idx & 31) * 4;
            *(float4*)&h_lds[r][f] = v;
        }
    }
    __syncthreads();

    // each wave computes 16 rows; lane = output feature o
    const float a1 = a[lane];
    const float a2 = a[64 + lane];
    float acc[16];
    #pragma unroll
    for (int r = 0; r < 16; ++r) acc[r] = 0.0f;

    for (int f = 0; f < 128; f += 4) {
        const float w0 = W[(f+0)*64 + lane];
        const float w1 = W[(f+1)*64 + lane];
        const float w2 = W[(f+2)*64 + lane];
        const float w3 = W[(f+3)*64 + lane];
        #pragma unroll
        for (int r = 0; r < 16; ++r) {
            const float4 hv = *(const float4*)&h_lds[wave*16 + r][f];  // broadcast
            acc[r] = fmaf(hv.x, w0, acc[r]);
            acc[r] = fmaf(hv.y, w1, acc[r]);
            acc[r] = fmaf(hv.z, w2, acc[r]);
            acc[r] = fmaf(hv.w, w3, acc[r]);
        }
    }

    #pragma unroll
    for (int r = 0; r < 16; ++r) {
        const int rr = wave*16 + r;
        wh_lds[rr][lane] = acc[r];
        float s1 = acc[r] * a1;
        float s2 = acc[r] * a2;
        #pragma unroll
        for (int off = 32; off > 0; off >>= 1) {
            s1 += __shfl_xor(s1, off);
            s2 += __shfl_xor(s2, off);
        }
        if (lane == 0) {
            si[row0 + rr] = s1;
            sj[row0 + rr] = s2;
        }
    }
    __syncthreads();

    // transposed bf16 write: WhT[b][o][n0..n0+63]
    const long long b  = row0 >> 11;          // /2048 (64 | 2048 so same batch)
    const int n0 = (int)(row0 & 2047);
    const int o  = tid >> 2;
    const int c0 = (tid & 3) * 16;
    unsigned short* dst = WhT + (b*64 + o)*2048 + n0 + c0;
    u16x8 v0, v1;
    #pragma unroll
    for (int k = 0; k < 8; ++k) v0[k] = f2bf(wh_lds[c0 + k][o]);
    #pragma unroll
    for (int k = 0; k < 8; ++k) v1[k] = f2bf(wh_lds[c0 + 8 + k][o]);
    *(u16x8*)dst       = v0;
    *(u16x8*)(dst + 8) = v1;
}

// ---------------------------------------------------------------------------
// Kernel B: fused masked-softmax attention, flash-style.
// Block = (batch b, 16-row i-tile); 4 waves, each owns a 512-wide j-quarter.
// Per 32-j chunk: adj loads -> e -> online softmax -> P (bf16, A-fragment
// layout) -> 4x mfma_f32_16x16x32_bf16 against WhT fragments.
// The k<->(group,elem) mapping is the same bijection for A and B, so any
// HW k-ordering cancels. C/D layout (verified): col=lane&15, row=(l>>4)*4+reg.
// ---------------------------------------------------------------------------
__global__ __launch_bounds__(256) void gat_attention(
    const int* __restrict__ adj, const unsigned short* __restrict__ WhT,
    const float* __restrict__ si, const float* __restrict__ sj,
    float* __restrict__ out)
{
    __shared__ float m_lds[4][16];
    __shared__ float l_lds[4][16];
    __shared__ float acc_lds[4][16][64];

    const int tid  = threadIdx.x;
    const int lane = tid & 63;
    const int wave = tid >> 6;           // j-quarter owner
    const int bid  = blockIdx.x;
    const int b    = bid >> 7;           // /128 i-tiles per batch
    const int i0   = (bid & 127) << 4;   // *16

    const int arow = lane & 15;          // A-row (and B/C column-within-block)
    const int g    = lane >> 4;          // k-group

    const long long adj_base = (((long long)b * 2048) + i0 + arow) * 2048;
    const float* sjb = sj + b * 2048;
    const float  mysi = si[b * 2048 + i0 + arow];
    const unsigned short* whb = WhT + (long long)b * 64 * 2048;

    f32x4 accf[4];
    #pragma unroll
    for (int ob = 0; ob < 4; ++ob) accf[ob] = (f32x4){0.f, 0.f, 0.f, 0.f};
    float m = -INFINITY;
    float l = 0.0f;

    const int jbase = wave * 512;

    for (int jc = 0; jc < 512; jc += 32) {
        const int jl = jbase + jc + g * 8;     // this lane's 8 j's
        const i32x4 A0 = *(const i32x4*)(adj + adj_base + jl);
        const i32x4 A1 = *(const i32x4*)(adj + adj_base + jl + 4);
        const f32x4 S0 = *(const f32x4*)(sjb + jl);
        const f32x4 S1 = *(const f32x4*)(sjb + jl + 4);

        float e[8];
        #pragma unroll
        for (int k = 0; k < 4; ++k) e[k]     = mysi + S0[k];
        #pragma unroll
        for (int k = 0; k < 4; ++k) e[4 + k] = mysi + S1[k];
        #pragma unroll
        for (int k = 0; k < 8; ++k) e[k] = e[k] > 0.f ? e[k] : ALPHA * e[k];
        #pragma unroll
        for (int k = 0; k < 4; ++k) e[k]     = A0[k] > 0 ? e[k]     : NEG_BIG;
        #pragma unroll
        for (int k = 0; k < 4; ++k) e[4 + k] = A1[k] > 0 ? e[4 + k] : NEG_BIG;

        // per-row chunk max: in-lane over 8, then across 4 k-groups
        float cm = fmaxf(fmaxf(fmaxf(e[0], e[1]), fmaxf(e[2], e[3])),
                         fmaxf(fmaxf(e[4], e[5]), fmaxf(e[6], e[7])));
        cm = fmaxf(cm, __shfl_xor(cm, 16));
        cm = fmaxf(cm, __shfl_xor(cm, 32));
        const float mnew  = fmaxf(m, cm);
        const float scale = __expf(m - mnew);   // first chunk: exp(-inf)=0
        m = mnew;

        float p[8];
        float csum = 0.f;
        #pragma unroll
        for (int k = 0; k < 8; ++k) { p[k] = __expf(e[k] - mnew); csum += p[k]; }
        csum += __shfl_xor(csum, 16);
        csum += __shfl_xor(csum, 32);
        l = l * scale + csum;

        // rescale C-fragments: C row = g*4+reg, its scale lives in lane g*4+reg
        const float cs0 = __shfl(scale, g*4 + 0);
        const float cs1 = __shfl(scale, g*4 + 1);
        const float cs2 = __shfl(scale, g*4 + 2);
        const float cs3 = __shfl(scale, g*4 + 3);
        #pragma unroll
        for (int ob = 0; ob < 4; ++ob) {
            accf[ob][0] *= cs0; accf[ob][1] *= cs1;
            accf[ob][2] *= cs2; accf[ob][3] *= cs3;
        }

        bf16x8 pa;
        #pragma unroll
        for (int k = 0; k < 8; ++k) pa[k] = (short)f2bf(p[k]);

        #pragma unroll
        for (int ob = 0; ob < 4; ++ob) {
            const bf16x8 bfr = *(const bf16x8*)(whb + (long long)(ob*16 + arow)*2048 + jl);
            accf[ob] = __builtin_amdgcn_mfma_f32_16x16x32_bf16(pa, bfr, accf[ob], 0, 0, 0);
        }
    }

    // ---- combine the 4 j-quarter partials ----
    if (g == 0) { m_lds[wave][arow] = m; l_lds[wave][arow] = l; }
    __syncthreads();

    #pragma unroll
    for (int r = 0; r < 4; ++r) {
        const int cr = g*4 + r;
        const float M  = fmaxf(fmaxf(m_lds[0][cr], m_lds[1][cr]),
                               fmaxf(m_lds[2][cr], m_lds[3][cr]));
        const float ws = __expf(m_lds[wave][cr] - M);
        #pragma unroll
        for (int ob = 0; ob < 4; ++ob)
            acc_lds[wave][cr][ob*16 + arow] = accf[ob][r] * ws;
    }
    __syncthreads();

    const int oo = tid & 63;
    for (int rr = tid >> 6; rr < 16; rr += 4) {
        const float M = fmaxf(fmaxf(m_lds[0][rr], m_lds[1][rr]),
                              fmaxf(m_lds[2][rr], m_lds[3][rr]));
        const float L = l_lds[0][rr]*__expf(m_lds[0][rr]-M)
                      + l_lds[1][rr]*__expf(m_lds[1][rr]-M)
                      + l_lds[2][rr]*__expf(m_lds[2][rr]-M)
                      + l_lds[3][rr]*__expf(m_lds[3][rr]-M);
        const float s = acc_lds[0][rr][oo] + acc_lds[1][rr][oo]
                      + acc_lds[2][rr][oo] + acc_lds[3][rr][oo];
        out[(((long long)b*2048) + i0 + rr)*64 + oo] = s / L;
    }
}

// ---------------------------------------------------------------------------
extern "C" void kernel_launch(void* const* d_in, const int* in_sizes, int n_in,
                              void* d_out, int out_size, void* d_ws, size_t ws_size,
                              hipStream_t stream) {
    const float* h   = (const float*)d_in[0];
    const int*   adj = (const int*)d_in[1];
    const float* W   = (const float*)d_in[2];
    const float* a   = (const float*)d_in[3];
    float* out = (float*)d_out;

    // workspace: WhT bf16 [8][64][2048] (2 MB) + si/sj fp32 [16384] each
    unsigned short* WhT = (unsigned short*)d_ws;
    float* si = (float*)((char*)d_ws + (size_t)8*64*2048*2);
    float* sj = si + 8*2048;

    gat_precompute<<<256, 256, 0, stream>>>(h, W, a, WhT, si, sj);
    gat_attention<<<1024, 256, 0, stream>>>(adj, WhT, si, sj, out);
}